// Round 8
// baseline (704.618 us; speedup 1.0000x reference)
//
#include <hip/hip_runtime.h>
#include <hip/hip_bf16.h>

#define DIM 128
#define NSLICE 4
#define SL_DW 16    // dwords per slice (16 dwords = 32 feats = 64 B)
typedef unsigned int u32;

// bf16x2 pack/unpack: low ushort = even feature, high = odd feature.
__device__ __forceinline__ u32 pack_bf16x2(float a, float b) {
    u32 ua = __float_as_uint(a), ub = __float_as_uint(b);
    ua = (ua + 0x7FFFu + ((ua >> 16) & 1u)) >> 16;        // RNE
    ub = (ub + 0x7FFFu + ((ub >> 16) & 1u)) >> 16;
    return ua | (ub << 16);
}
__device__ __forceinline__ float2 unpack_bf16x2(u32 h) {
    return make_float2(__uint_as_float(h << 16), __uint_as_float(h & 0xFFFF0000u));
}

// ======================= CSR build =======================

__global__ void edge_count(int* __restrict__ deg, const int* __restrict__ dst, int E) {
    int e = blockIdx.x * blockDim.x + threadIdx.x;
    if (e < E) atomicAdd(&deg[dst[e]], 1);
}

// Bucket starts padded to multiples of 4 (pad slots zero-filled: nrm=0).
__global__ __launch_bounds__(256) void alloc_offsets(
    const int* __restrict__ deg, int* __restrict__ start, int* __restrict__ end_,
    int* __restrict__ cursor, float* __restrict__ dinv, int* total, int N)
{
    int i = blockIdx.x * blockDim.x + threadIdx.x;
    int lane = threadIdx.x & 63;
    int d  = (i < N) ? deg[i] : 0;
    int d4 = (d + 3) & ~3;
    int pre = d4;
    #pragma unroll
    for (int off = 1; off < 64; off <<= 1) {
        int v = __shfl_up(pre, off, 64);
        if (lane >= off) pre += v;
    }
    int waveTot = __shfl(pre, 63, 64);
    int base = 0;
    if (lane == 63) base = atomicAdd(total, waveTot);
    base = __shfl(base, 63, 64);
    if (i < N) {
        int st = base + pre - d4;
        start[i]  = st;
        end_[i]   = st + d;
        cursor[i] = st;
        dinv[i]   = rsqrtf((float)(d + 1));   // +1 self-loop
    }
}

__global__ void scatter_edges(const int* __restrict__ src, const int* __restrict__ dst,
                              const float* __restrict__ dinv, int* __restrict__ cursor,
                              int* __restrict__ csr_src, float* __restrict__ csr_nrm, int E)
{
    int e = blockIdx.x * blockDim.x + threadIdx.x;
    if (e >= E) return;
    int s = src[e], d = dst[e];
    int p = atomicAdd(&cursor[d], 1);
    csr_src[p] = s;
    csr_nrm[p] = dinv[s] * dinv[d];
}

// ============== feature-sliced, XCD-affine gather aggregation ==============
// slice = blockIdx.x % 4 -> with %8 round-robin block->XCD dispatch, each XCD
// always touches one 3.2 MB feature slice of H -> L2-resident, row reads hit.
// One wave per (node, slice). Lane l: edge sub-index e_off=l>>4, dword d=l&15.
// Per iteration a wave-load covers 4 edges x 64 B aligned row-slices.
template<int FUSE_POOL>
__global__ __launch_bounds__(256) void gather_sliced(
    const u32* __restrict__ H, u32* __restrict__ O,
    const int* __restrict__ csr_src, const float* __restrict__ csr_nrm,
    const int* __restrict__ start, const int* __restrict__ end_,
    const float* __restrict__ dinv, int N,
    const float* __restrict__ b2, const float* __restrict__ wlin,
    const int* __restrict__ batch, float* __restrict__ sums, float* __restrict__ cnt)
{
    const int slice = blockIdx.x & (NSLICE - 1);
    const int node  = (blockIdx.x >> 2) * 4 + (threadIdx.x >> 6);
    const int lane  = threadIdx.x & 63;
    if (node >= N) return;

    const int e_off = lane >> 4;        // 0..3
    const int d     = lane & 15;        // dword within slice
    const u32* Hs = H + slice * SL_DW + d;   // row stride 64 dwords

    int st = start[node], en = end_[node];
    int en_pad = st + ((en - st + 3) & ~3);

    float2 acc = {0.f, 0.f};
    int j = st;
    for (; j + 8 <= en_pad; j += 8) {
        int   sA = csr_src[j + e_off];
        int   sB = csr_src[j + 4 + e_off];
        float nA = csr_nrm[j + e_off];
        float nB = csr_nrm[j + 4 + e_off];
        u32 rA = Hs[(size_t)sA * 64];
        u32 rB = Hs[(size_t)sB * 64];
        float2 hA = unpack_bf16x2(rA), hB = unpack_bf16x2(rB);
        acc.x = fmaf(hA.x, nA, acc.x);  acc.y = fmaf(hA.y, nA, acc.y);
        acc.x = fmaf(hB.x, nB, acc.x);  acc.y = fmaf(hB.y, nB, acc.y);
    }
    if (j < en_pad) {   // one 4-chunk
        int   s = csr_src[j + e_off];
        float n = csr_nrm[j + e_off];
        float2 h = unpack_bf16x2(Hs[(size_t)s * 64]);
        acc.x = fmaf(h.x, n, acc.x);  acc.y = fmaf(h.y, n, acc.y);
    }

    // reduce across the 4 e_off groups (lanes d, d+16, d+32, d+48)
    acc.x += __shfl_xor(acc.x, 16, 64);
    acc.y += __shfl_xor(acc.y, 16, 64);
    acc.x += __shfl_xor(acc.x, 32, 64);
    acc.y += __shfl_xor(acc.y, 32, 64);

    // self-loop term (post-reduce, once per dword)
    float di = dinv[node];
    float nn = di * di;
    float2 self = unpack_bf16x2(Hs[(size_t)node * 64]);
    float2 res = make_float2(fmaf(self.x, nn, acc.x), fmaf(self.y, nn, acc.y));

    if (FUSE_POOL) {
        int f = slice * 32 + 2 * d;
        float v = fmaxf(res.x + b2[f], 0.f)     * wlin[f]
                + fmaxf(res.y + b2[f + 1], 0.f) * wlin[f + 1];
        // sum the 16 dwords (lanes 16..63 duplicate d=0..15 within their group,
        // but each 16-lane xor-group reduces exactly d=0..15 once)
        #pragma unroll
        for (int m = 1; m <= 8; m <<= 1) v += __shfl_xor(v, m, 64);
        if (lane == 0) {
            int g = batch[node];
            unsafeAtomicAdd(&sums[g], v);
            if (slice == 0) unsafeAtomicAdd(&cnt[g], 1.0f);
        }
    } else {
        if (lane < 16)
            O[(size_t)node * 64 + slice * SL_DW + d] = pack_bf16x2(res.x, res.y);
    }
}

// ======================= GEMM =======================
// Y[node][f] = sum_k X'[node][k] * W[k][f]; W fp32; Y bf16.
// MODE 0: X fp32 (the raw input x). MODE 1: X bf16 + bias + relu.
// BM=64 x BN=128 x BK=32 LDS outer product; thread tile 8 nodes x 4 feats.

template<int MODE>
__global__ __launch_bounds__(256) void gemm_nodes(
    const void* __restrict__ Xv,
    const float* __restrict__ bias,
    const float* __restrict__ W,   // [128][128] row-major (k, f)
    u32* __restrict__ Y, int N)
{
    __shared__ float As[32][72];
    __shared__ float Bs[32][132];
    const int t = threadIdx.x;
    const int node0 = blockIdx.x * 64;
    const int tx = t & 31;
    const int ty = t >> 5;
    const int f0 = tx * 4;
    const int n0 = ty * 8;

    float acc[8][4];
    #pragma unroll
    for (int i = 0; i < 8; ++i)
        #pragma unroll
        for (int j = 0; j < 4; ++j) acc[i][j] = 0.f;

    const int sr  = t >> 3;
    const int sc4 = (t & 7) * 4;

    for (int k0 = 0; k0 < DIM; k0 += 32) {
        #pragma unroll
        for (int half = 0; half < 2; ++half) {
            int r = sr + half * 32;
            int node = node0 + r;
            float v[4] = {0.f, 0.f, 0.f, 0.f};
            if (node < N) {
                if (MODE == 0) {
                    const float* X = (const float*)Xv;
                    *(float4*)v = *(const float4*)&X[(size_t)node * DIM + k0 + sc4];
                } else {
                    const u32* X = (const u32*)Xv;
                    uint2 q = *(const uint2*)&X[(size_t)node * 64 + (k0 + sc4) / 2];
                    float2 ab = unpack_bf16x2(q.x);
                    float2 cd = unpack_bf16x2(q.y);
                    v[0] = ab.x; v[1] = ab.y; v[2] = cd.x; v[3] = cd.y;
                }
            }
            if (MODE == 1) {
                float bv[4];
                *(float4*)bv = *(const float4*)&bias[k0 + sc4];
                #pragma unroll
                for (int i = 0; i < 4; ++i) v[i] = fmaxf(v[i] + bv[i], 0.f);
                if (node >= N) { v[0]=v[1]=v[2]=v[3]=0.f; }
            }
            #pragma unroll
            for (int i = 0; i < 4; ++i) As[sc4 + i][r] = v[i];
        }
        #pragma unroll
        for (int i = 0; i < 4; ++i) {
            int kk = (t >> 5) + i * 8;
            float4 wv = *(const float4*)&W[(size_t)(k0 + kk) * DIM + f0];
            *(float4*)&Bs[kk][f0] = wv;
        }
        __syncthreads();

        #pragma unroll 4
        for (int kk = 0; kk < 32; ++kk) {
            float4 a0 = *(const float4*)&As[kk][n0];
            float4 a1 = *(const float4*)&As[kk][n0 + 4];
            float4 b  = *(const float4*)&Bs[kk][f0];
            float av[8] = {a0.x,a0.y,a0.z,a0.w,a1.x,a1.y,a1.z,a1.w};
            float bv[4] = {b.x,b.y,b.z,b.w};
            #pragma unroll
            for (int i = 0; i < 8; ++i)
                #pragma unroll
                for (int j = 0; j < 4; ++j)
                    acc[i][j] = fmaf(av[i], bv[j], acc[i][j]);
        }
        __syncthreads();
    }

    #pragma unroll
    for (int i = 0; i < 8; ++i) {
        int node = node0 + n0 + i;
        if (node < N) {
            uint2 o;
            o.x = pack_bf16x2(acc[i][0], acc[i][1]);
            o.y = pack_bf16x2(acc[i][2], acc[i][3]);
            *(uint2*)&Y[(size_t)node * 64 + f0 / 2] = o;
        }
    }
}

__global__ void final_kernel(const float* __restrict__ sums,
                             const float* __restrict__ cnt,
                             const float* __restrict__ blin,
                             float* __restrict__ out, int G)
{
    int g = blockIdx.x * blockDim.x + threadIdx.x;
    if (g < G) out[g] = sums[g] / fmaxf(cnt[g], 1.0f) + blin[0];
}

// ======================= launch =======================

extern "C" void kernel_launch(void* const* d_in, const int* in_sizes, int n_in,
                              void* d_out, int out_size, void* d_ws, size_t ws_size,
                              hipStream_t stream)
{
    const float* x    = (const float*)d_in[0];
    const int*   src  = (const int*)d_in[1];
    const int*   dst  = (const int*)d_in[2];
    const int*   batch= (const int*)d_in[3];
    const float* W1   = (const float*)d_in[5];
    const float* b1   = (const float*)d_in[6];
    const float* W2   = (const float*)d_in[7];
    const float* b2   = (const float*)d_in[8];
    const float* wlin = (const float*)d_in[9];
    const float* blin = (const float*)d_in[10];
    float* out = (float*)d_out;

    const int N = in_sizes[0] / DIM;
    const int E = in_sizes[1];
    const int G = out_size;
    const size_t E_pad = (size_t)E + 4 * (size_t)N;   // per-bucket pad to x4

    // layout: B0(bf16 N*64 u32), B1(bf16), dinv(N), sums(G), cnt(G),
    //         deg/cursor(N), start(N), end(N), csr_src(E_pad), csr_nrm(E_pad), total
    u32*   B0    = (u32*)d_ws;
    u32*   B1    = B0 + (size_t)N * 64;
    float* dinv  = (float*)(B1 + (size_t)N * 64);
    float* sums  = dinv + N;
    float* cnt   = sums + G;
    int*   deg_c = (int*)(cnt + G);
    int*   start = deg_c + N;
    int*   end_  = start + N;
    int*   csrs  = end_ + N;
    float* csrn  = (float*)(csrs + E_pad);
    int*   total = (int*)(csrn + E_pad);
    size_t need_bytes = ((size_t)(total + 1) - (size_t)d_ws);
    if (ws_size < need_bytes) return;   // not expected: ws has always sufficed

    const int gblocks = (N + 63) / 64;
    const int eblocks = (E + 255) / 256;
    const int sblocks = ((N + 3) / 4) * NSLICE;

    // ---- CSR build (once, reused by both layers) ----
    hipMemsetAsync(deg_c, 0, sizeof(int) * (size_t)N, stream);
    hipMemsetAsync(total, 0, sizeof(int), stream);
    hipMemsetAsync(sums, 0, sizeof(float) * 2 * (size_t)G, stream);
    hipMemsetAsync(csrs, 0, sizeof(int) * 2 * E_pad, stream);  // zero pad slots
    edge_count<<<eblocks, 256, 0, stream>>>(deg_c, dst, E);
    alloc_offsets<<<(N + 255) / 256, 256, 0, stream>>>(deg_c, start, end_, deg_c,
                                                       dinv, total, N);
    scatter_edges<<<eblocks, 256, 0, stream>>>(src, dst, dinv, deg_c, csrs, csrn, E);

    // ---- layer 1 ----
    gemm_nodes<0><<<gblocks, 256, 0, stream>>>(x, nullptr, W1, B0, N);
    gather_sliced<0><<<sblocks, 256, 0, stream>>>(B0, B1, csrs, csrn, start, end_,
                                                  dinv, N, nullptr, nullptr,
                                                  nullptr, nullptr, nullptr);
    // ---- layer 2 (gather fused with pooling) ----
    gemm_nodes<1><<<gblocks, 256, 0, stream>>>(B1, b1, W2, B0, N);
    gather_sliced<1><<<sblocks, 256, 0, stream>>>(B0, nullptr, csrs, csrn, start,
                                                  end_, dinv, N, b2, wlin,
                                                  batch, sums, cnt);
    final_kernel<<<(G + 255) / 256, 256, 0, stream>>>(sums, cnt, blin, out, G);
}

// Round 9
// 349.420 us; speedup vs baseline: 2.0165x; 2.0165x over previous
//
#include <hip/hip_runtime.h>
#include <hip/hip_bf16.h>

#define DIM 128
typedef unsigned int u32;

// bf16x2 pack/unpack: low ushort = even feature, high = odd feature.
__device__ __forceinline__ u32 pack_bf16x2(float a, float b) {
    u32 ua = __float_as_uint(a), ub = __float_as_uint(b);
    ua = (ua + 0x7FFFu + ((ua >> 16) & 1u)) >> 16;        // RNE
    ub = (ub + 0x7FFFu + ((ub >> 16) & 1u)) >> 16;
    return ua | (ub << 16);
}
__device__ __forceinline__ float2 unpack_bf16x2(u32 h) {
    return make_float2(__uint_as_float(h << 16), __uint_as_float(h & 0xFFFF0000u));
}

__device__ __forceinline__ void accum8(float* acc, uint4 r, float n) {
    float2 p0 = unpack_bf16x2(r.x), p1 = unpack_bf16x2(r.y);
    float2 p2 = unpack_bf16x2(r.z), p3 = unpack_bf16x2(r.w);
    acc[0] = fmaf(p0.x, n, acc[0]); acc[1] = fmaf(p0.y, n, acc[1]);
    acc[2] = fmaf(p1.x, n, acc[2]); acc[3] = fmaf(p1.y, n, acc[3]);
    acc[4] = fmaf(p2.x, n, acc[4]); acc[5] = fmaf(p2.y, n, acc[5]);
    acc[6] = fmaf(p3.x, n, acc[6]); acc[7] = fmaf(p3.y, n, acc[7]);
}

// ======================= CSR build =======================

__global__ void edge_count(int* __restrict__ deg, const int* __restrict__ dst, int E) {
    int e = blockIdx.x * blockDim.x + threadIdx.x;
    if (e < E) atomicAdd(&deg[dst[e]], 1);
}

// Bucket starts padded to multiples of 4 (pad slots zero-filled: nrm=0).
__global__ __launch_bounds__(256) void alloc_offsets(
    const int* __restrict__ deg, int* __restrict__ start, int* __restrict__ end_,
    int* __restrict__ cursor, float* __restrict__ dinv, int* total, int N)
{
    int i = blockIdx.x * blockDim.x + threadIdx.x;
    int lane = threadIdx.x & 63;
    int d  = (i < N) ? deg[i] : 0;
    int d4 = (d + 3) & ~3;
    int pre = d4;
    #pragma unroll
    for (int off = 1; off < 64; off <<= 1) {
        int v = __shfl_up(pre, off, 64);
        if (lane >= off) pre += v;
    }
    int waveTot = __shfl(pre, 63, 64);
    int base = 0;
    if (lane == 63) base = atomicAdd(total, waveTot);
    base = __shfl(base, 63, 64);
    if (i < N) {
        int st = base + pre - d4;
        start[i]  = st;
        end_[i]   = st + d;
        cursor[i] = st;
        dinv[i]   = rsqrtf((float)(d + 1));   // +1 self-loop
    }
}

__global__ void scatter_edges(const int* __restrict__ src, const int* __restrict__ dst,
                              const float* __restrict__ dinv, int* __restrict__ cursor,
                              int* __restrict__ csr_src, float* __restrict__ csr_nrm, int E)
{
    int e = blockIdx.x * blockDim.x + threadIdx.x;
    if (e >= E) return;
    int s = src[e], d = dst[e];
    int p = atomicAdd(&cursor[d], 1);
    csr_src[p] = s;
    csr_nrm[p] = dinv[s] * dinv[d];
}

// ======================= gather aggregation (4 nodes / wave) ==============
// 16 lanes per node; lane gl holds dwords 4gl..4gl+3 (features 8gl..8gl+7).
// One wave row-load instruction covers 4 rows x 256 B = 1 KB (16 B/lane).
// Bucket lengths are multiples of 4 -> inner loop has no scalar tail.
template<int FUSE_POOL>
__global__ __launch_bounds__(256) void gather4(
    const u32* __restrict__ H, u32* __restrict__ O,
    const int* __restrict__ csr_src, const float* __restrict__ csr_nrm,
    const int* __restrict__ start, const int* __restrict__ end_,
    const float* __restrict__ dinv, int N,
    const float* __restrict__ b2, const float* __restrict__ wlin,
    const int* __restrict__ batch, float* __restrict__ sums, float* __restrict__ cnt)
{
    const int grp  = threadIdx.x >> 4;          // 0..15
    const int gl   = threadIdx.x & 15;          // lane within group
    const int node = blockIdx.x * 16 + grp;
    if (node >= N) return;

    const u32* Hl = H + gl * 4;                 // row stride 64 dwords

    int st = start[node], en = end_[node];
    int en_pad = st + ((en - st + 3) & ~3);

    float acc[8] = {0.f,0.f,0.f,0.f,0.f,0.f,0.f,0.f};

    int j = st;
    for (; j + 8 <= en_pad; j += 8) {
        int4   sa = *(const int4*)  &csr_src[j];
        int4   sb = *(const int4*)  &csr_src[j + 4];
        float4 na = *(const float4*)&csr_nrm[j];
        float4 nb = *(const float4*)&csr_nrm[j + 4];
        uint4 r0 = *(const uint4*)&Hl[(size_t)sa.x * 64];
        uint4 r1 = *(const uint4*)&Hl[(size_t)sa.y * 64];
        uint4 r2 = *(const uint4*)&Hl[(size_t)sa.z * 64];
        uint4 r3 = *(const uint4*)&Hl[(size_t)sa.w * 64];
        uint4 r4 = *(const uint4*)&Hl[(size_t)sb.x * 64];
        uint4 r5 = *(const uint4*)&Hl[(size_t)sb.y * 64];
        uint4 r6 = *(const uint4*)&Hl[(size_t)sb.z * 64];
        uint4 r7 = *(const uint4*)&Hl[(size_t)sb.w * 64];
        accum8(acc, r0, na.x);  accum8(acc, r1, na.y);
        accum8(acc, r2, na.z);  accum8(acc, r3, na.w);
        accum8(acc, r4, nb.x);  accum8(acc, r5, nb.y);
        accum8(acc, r6, nb.z);  accum8(acc, r7, nb.w);
    }
    if (j < en_pad) {   // exactly one 4-chunk
        int4   sa = *(const int4*)  &csr_src[j];
        float4 na = *(const float4*)&csr_nrm[j];
        uint4 r0 = *(const uint4*)&Hl[(size_t)sa.x * 64];
        uint4 r1 = *(const uint4*)&Hl[(size_t)sa.y * 64];
        uint4 r2 = *(const uint4*)&Hl[(size_t)sa.z * 64];
        uint4 r3 = *(const uint4*)&Hl[(size_t)sa.w * 64];
        accum8(acc, r0, na.x);  accum8(acc, r1, na.y);
        accum8(acc, r2, na.z);  accum8(acc, r3, na.w);
    }

    // self-loop
    float di = dinv[node];
    uint4 rs = *(const uint4*)&Hl[(size_t)node * 64];
    accum8(acc, rs, di * di);

    if (FUSE_POOL) {
        int f0 = gl * 8;
        float v = 0.f;
        #pragma unroll
        for (int i = 0; i < 8; ++i)
            v += fmaxf(acc[i] + b2[f0 + i], 0.f) * wlin[f0 + i];
        #pragma unroll
        for (int m = 1; m <= 8; m <<= 1) v += __shfl_xor(v, m, 64); // within group
        if (gl == 0) {
            int g = batch[node];
            unsafeAtomicAdd(&sums[g], v);
            unsafeAtomicAdd(&cnt[g], 1.0f);
        }
    } else {
        uint4 o;
        o.x = pack_bf16x2(acc[0], acc[1]);
        o.y = pack_bf16x2(acc[2], acc[3]);
        o.z = pack_bf16x2(acc[4], acc[5]);
        o.w = pack_bf16x2(acc[6], acc[7]);
        *(uint4*)&O[(size_t)node * 64 + gl * 4] = o;
    }
}

// ======================= GEMM =======================
// Y[node][f] = sum_k X'[node][k] * W[k][f]; W fp32; Y bf16.
// MODE 0: X fp32 (the raw input x). MODE 1: X bf16 + bias + relu.
// BM=64 x BN=128 x BK=32 LDS outer product; thread tile 8 nodes x 4 feats.

template<int MODE>
__global__ __launch_bounds__(256) void gemm_nodes(
    const void* __restrict__ Xv,
    const float* __restrict__ bias,
    const float* __restrict__ W,   // [128][128] row-major (k, f)
    u32* __restrict__ Y, int N)
{
    __shared__ float As[32][72];
    __shared__ float Bs[32][132];
    const int t = threadIdx.x;
    const int node0 = blockIdx.x * 64;
    const int tx = t & 31;
    const int ty = t >> 5;
    const int f0 = tx * 4;
    const int n0 = ty * 8;

    float acc[8][4];
    #pragma unroll
    for (int i = 0; i < 8; ++i)
        #pragma unroll
        for (int j = 0; j < 4; ++j) acc[i][j] = 0.f;

    const int sr  = t >> 3;
    const int sc4 = (t & 7) * 4;

    for (int k0 = 0; k0 < DIM; k0 += 32) {
        #pragma unroll
        for (int half = 0; half < 2; ++half) {
            int r = sr + half * 32;
            int node = node0 + r;
            float v[4] = {0.f, 0.f, 0.f, 0.f};
            if (node < N) {
                if (MODE == 0) {
                    const float* X = (const float*)Xv;
                    *(float4*)v = *(const float4*)&X[(size_t)node * DIM + k0 + sc4];
                } else {
                    const u32* X = (const u32*)Xv;
                    uint2 q = *(const uint2*)&X[(size_t)node * 64 + (k0 + sc4) / 2];
                    float2 ab = unpack_bf16x2(q.x);
                    float2 cd = unpack_bf16x2(q.y);
                    v[0] = ab.x; v[1] = ab.y; v[2] = cd.x; v[3] = cd.y;
                }
            }
            if (MODE == 1) {
                float bv[4];
                *(float4*)bv = *(const float4*)&bias[k0 + sc4];
                #pragma unroll
                for (int i = 0; i < 4; ++i) v[i] = fmaxf(v[i] + bv[i], 0.f);
                if (node >= N) { v[0]=v[1]=v[2]=v[3]=0.f; }
            }
            #pragma unroll
            for (int i = 0; i < 4; ++i) As[sc4 + i][r] = v[i];
        }
        #pragma unroll
        for (int i = 0; i < 4; ++i) {
            int kk = (t >> 5) + i * 8;
            float4 wv = *(const float4*)&W[(size_t)(k0 + kk) * DIM + f0];
            *(float4*)&Bs[kk][f0] = wv;
        }
        __syncthreads();

        #pragma unroll 4
        for (int kk = 0; kk < 32; ++kk) {
            float4 a0 = *(const float4*)&As[kk][n0];
            float4 a1 = *(const float4*)&As[kk][n0 + 4];
            float4 b  = *(const float4*)&Bs[kk][f0];
            float av[8] = {a0.x,a0.y,a0.z,a0.w,a1.x,a1.y,a1.z,a1.w};
            float bv[4] = {b.x,b.y,b.z,b.w};
            #pragma unroll
            for (int i = 0; i < 8; ++i)
                #pragma unroll
                for (int j = 0; j < 4; ++j)
                    acc[i][j] = fmaf(av[i], bv[j], acc[i][j]);
        }
        __syncthreads();
    }

    #pragma unroll
    for (int i = 0; i < 8; ++i) {
        int node = node0 + n0 + i;
        if (node < N) {
            uint2 o;
            o.x = pack_bf16x2(acc[i][0], acc[i][1]);
            o.y = pack_bf16x2(acc[i][2], acc[i][3]);
            *(uint2*)&Y[(size_t)node * 64 + f0 / 2] = o;
        }
    }
}

__global__ void final_kernel(const float* __restrict__ sums,
                             const float* __restrict__ cnt,
                             const float* __restrict__ blin,
                             float* __restrict__ out, int G)
{
    int g = blockIdx.x * blockDim.x + threadIdx.x;
    if (g < G) out[g] = sums[g] / fmaxf(cnt[g], 1.0f) + blin[0];
}

// ======================= launch =======================

extern "C" void kernel_launch(void* const* d_in, const int* in_sizes, int n_in,
                              void* d_out, int out_size, void* d_ws, size_t ws_size,
                              hipStream_t stream)
{
    const float* x    = (const float*)d_in[0];
    const int*   src  = (const int*)d_in[1];
    const int*   dst  = (const int*)d_in[2];
    const int*   batch= (const int*)d_in[3];
    const float* W1   = (const float*)d_in[5];
    const float* b1   = (const float*)d_in[6];
    const float* W2   = (const float*)d_in[7];
    const float* b2   = (const float*)d_in[8];
    const float* wlin = (const float*)d_in[9];
    const float* blin = (const float*)d_in[10];
    float* out = (float*)d_out;

    const int N = in_sizes[0] / DIM;
    const int E = in_sizes[1];
    const int G = out_size;
    const size_t E_pad = (size_t)E + 4 * (size_t)N;   // per-bucket pad to x4

    // layout: B0(bf16 N*64 u32), B1(bf16), dinv(N), sums(G), cnt(G),
    //         deg/cursor(N), start(N), end(N), csr_src(E_pad), csr_nrm(E_pad), total
    u32*   B0    = (u32*)d_ws;
    u32*   B1    = B0 + (size_t)N * 64;
    float* dinv  = (float*)(B1 + (size_t)N * 64);
    float* sums  = dinv + N;
    float* cnt   = sums + G;
    int*   deg_c = (int*)(cnt + G);
    int*   start = deg_c + N;
    int*   end_  = start + N;
    int*   csrs  = end_ + N;
    float* csrn  = (float*)(csrs + E_pad);
    int*   total = (int*)(csrn + E_pad);
    size_t need_bytes = ((size_t)(total + 1) - (size_t)d_ws);
    if (ws_size < need_bytes) return;   // not expected: ws has always sufficed

    const int gblocks = (N + 63) / 64;
    const int eblocks = (E + 255) / 256;
    const int g4blocks = (N + 15) / 16;

    // ---- CSR build (once, reused by both layers) ----
    hipMemsetAsync(deg_c, 0, sizeof(int) * (size_t)N, stream);
    hipMemsetAsync(total, 0, sizeof(int), stream);
    hipMemsetAsync(sums, 0, sizeof(float) * 2 * (size_t)G, stream);
    hipMemsetAsync(csrs, 0, sizeof(int) * 2 * E_pad, stream);  // zero pad slots
    edge_count<<<eblocks, 256, 0, stream>>>(deg_c, dst, E);
    alloc_offsets<<<(N + 255) / 256, 256, 0, stream>>>(deg_c, start, end_, deg_c,
                                                       dinv, total, N);
    scatter_edges<<<eblocks, 256, 0, stream>>>(src, dst, dinv, deg_c, csrs, csrn, E);

    // ---- layer 1 ----
    gemm_nodes<0><<<gblocks, 256, 0, stream>>>(x, nullptr, W1, B0, N);
    gather4<0><<<g4blocks, 256, 0, stream>>>(B0, B1, csrs, csrn, start, end_,
                                             dinv, N, nullptr, nullptr,
                                             nullptr, nullptr, nullptr);
    // ---- layer 2 (gather fused with pooling) ----
    gemm_nodes<1><<<gblocks, 256, 0, stream>>>(B1, b1, W2, B0, N);
    gather4<1><<<g4blocks, 256, 0, stream>>>(B0, nullptr, csrs, csrn, start,
                                             end_, dinv, N, b2, wlin,
                                             batch, sums, cnt);
    final_kernel<<<(G + 255) / 256, 256, 0, stream>>>(sums, cnt, blin, out, G);
}